// Round 1
// baseline (507.388 us; speedup 1.0000x reference)
//
#include <hip/hip_runtime.h>
#include <math.h>

// MagNet: B=32, N=512, F=AGG=128, FCH=256, NCLS=10, NLAYER=3
#define B_SZ   32
#define N_SZ   512
#define F_SZ   128
#define AGG_SZ 128
#define FCH_SZ 256
#define NCLS_SZ 10
#define NLAYER 3

constexpr int BM = 64, BN = 64, BK = 16;
constexpr int LDS_A = BM + 4;   // 68: keeps float4 alignment, breaks pow2 bank stride
constexpr int LDS_B = BN + 4;   // 68

// Complex GEMM: C[b] = A[b] * B[b] (+ optional complex-ReLU epilogue)
// A: [M x K] row-major (lda), B: [K x ldc] row-major (ldb), C: [M x ldc]
// HAS_BIM=0 -> B is purely real (layer-0 h = x). DO_RELU: zero (re,im) where re<0.
template<int HAS_BIM, int DO_RELU>
__global__ __launch_bounds__(256)
void cgemm_kernel(const float* __restrict__ Ar, const float* __restrict__ Ai,
                  long sA, int lda,
                  const float* __restrict__ Br, const float* __restrict__ Bi,
                  long sB, int ldb,
                  float* __restrict__ Cr, float* __restrict__ Ci,
                  long sC, int ldc, int K)
{
    __shared__ float As_re[BK][LDS_A];
    __shared__ float As_im[BK][LDS_A];
    __shared__ float Bs_re[BK][LDS_B];
    __shared__ float Bs_im[BK][LDS_B];

    const int t = threadIdx.x;
    const int b = blockIdx.z;
    const int rowBase = blockIdx.y * BM;
    const int colBase = blockIdx.x * BN;

    const int tx = t & 15;          // col group -> cols tx*4 .. tx*4+3
    const int ty = t >> 4;          // row group -> rows ty*4 .. ty*4+3

    const float* ArB = Ar + (long)b * sA;
    const float* AiB = Ai + (long)b * sA;
    const float* BrB = Br + (long)b * sB;
    const float* BiB = HAS_BIM ? (Bi + (long)b * sB) : nullptr;

    // A staging: thread loads float4 at (row=ar, k=ac..ac+3), stores k-major
    const int ar = t >> 2;          // 0..63
    const int ac = (t & 3) * 4;     // 0,4,8,12
    // B staging: thread loads float4 at (k=br, col=bc..bc+3)
    const int br = t >> 4;          // 0..15
    const int bc = (t & 15) * 4;    // 0..60

    float cr[4][4] = {{0.f}}, ci[4][4] = {{0.f}};

    for (int k0 = 0; k0 < K; k0 += BK) {
        const float4 va_re = *(const float4*)(ArB + (long)(rowBase + ar) * lda + k0 + ac);
        const float4 va_im = *(const float4*)(AiB + (long)(rowBase + ar) * lda + k0 + ac);
        As_re[ac + 0][ar] = va_re.x; As_re[ac + 1][ar] = va_re.y;
        As_re[ac + 2][ar] = va_re.z; As_re[ac + 3][ar] = va_re.w;
        As_im[ac + 0][ar] = va_im.x; As_im[ac + 1][ar] = va_im.y;
        As_im[ac + 2][ar] = va_im.z; As_im[ac + 3][ar] = va_im.w;

        *(float4*)&Bs_re[br][bc] = *(const float4*)(BrB + (long)(k0 + br) * ldb + colBase + bc);
        if (HAS_BIM)
            *(float4*)&Bs_im[br][bc] = *(const float4*)(BiB + (long)(k0 + br) * ldb + colBase + bc);

        __syncthreads();

        #pragma unroll
        for (int k = 0; k < BK; ++k) {
            const float4 fa_re = *(const float4*)&As_re[k][ty * 4];
            const float4 fa_im = *(const float4*)&As_im[k][ty * 4];
            const float4 fb_re = *(const float4*)&Bs_re[k][tx * 4];
            float4 fb_im;
            if (HAS_BIM) fb_im = *(const float4*)&Bs_im[k][tx * 4];
            const float* ar_ = (const float*)&fa_re;
            const float* ai_ = (const float*)&fa_im;
            const float* br_ = (const float*)&fb_re;
            const float* bi_ = (const float*)&fb_im;
            #pragma unroll
            for (int i = 0; i < 4; ++i) {
                #pragma unroll
                for (int j = 0; j < 4; ++j) {
                    cr[i][j] = fmaf(ar_[i], br_[j], cr[i][j]);
                    ci[i][j] = fmaf(ai_[i], br_[j], ci[i][j]);
                    if (HAS_BIM) {
                        cr[i][j] = fmaf(-ai_[i], bi_[j], cr[i][j]);
                        ci[i][j] = fmaf(ar_[i], bi_[j], ci[i][j]);
                    }
                }
            }
        }
        __syncthreads();
    }

    // epilogue
    #pragma unroll
    for (int i = 0; i < 4; ++i) {
        const long row = rowBase + ty * 4 + i;
        float4 vr, vi;
        float* pr = (float*)&vr;
        float* pi = (float*)&vi;
        #pragma unroll
        for (int j = 0; j < 4; ++j) {
            float re = cr[i][j], im = ci[i][j];
            if (DO_RELU) { if (re < 0.f) { re = 0.f; im = 0.f; } }
            pr[j] = re; pi[j] = im;
        }
        *(float4*)(Cr + (long)b * sC + row * ldc + colBase + tx * 4) = vr;
        *(float4*)(Ci + (long)b * sC + row * ldc + colBase + tx * 4) = vi;
    }
}

// mean over nodes -> feat[b][0:128]=Re mean, feat[b][128:256]=Im mean
__global__ __launch_bounds__(256)
void readout_kernel(const float* __restrict__ Hre, const float* __restrict__ Him,
                    float* __restrict__ feat)
{
    const int b = blockIdx.x;
    const int t = threadIdx.x;            // 0..255
    const int f = t & (F_SZ - 1);
    const float* src = ((t < F_SZ) ? Hre : Him) + (long)b * N_SZ * F_SZ + f;
    float s = 0.f;
    #pragma unroll 8
    for (int n = 0; n < N_SZ; ++n) s += src[(long)n * F_SZ];
    feat[b * (2 * AGG_SZ) + t] = s * (1.0f / N_SZ);
}

// fc1+relu -> fc2 -> softmax, one block per batch row
__global__ __launch_bounds__(256)
void head_kernel(const float* __restrict__ feat,
                 const float* __restrict__ w1, const float* __restrict__ b1,
                 const float* __restrict__ w2, const float* __restrict__ b2,
                 float* __restrict__ out)
{
    __shared__ float sf[2 * AGG_SZ];
    __shared__ float sz[FCH_SZ];
    __shared__ float sl[NCLS_SZ];

    const int b = blockIdx.x;
    const int t = threadIdx.x;            // 0..255 (== FCH)

    sf[t] = feat[b * (2 * AGG_SZ) + t];
    __syncthreads();

    float acc = b1[t];
    const float* wrow = w1 + (long)t * (2 * AGG_SZ);
    #pragma unroll 8
    for (int j = 0; j < 2 * AGG_SZ; ++j) acc = fmaf(sf[j], wrow[j], acc);
    sz[t] = fmaxf(acc, 0.f);
    __syncthreads();

    if (t < NCLS_SZ) {
        float l = b2[t];
        const float* w2r = w2 + (long)t * FCH_SZ;
        #pragma unroll 8
        for (int j = 0; j < FCH_SZ; ++j) l = fmaf(sz[j], w2r[j], l);
        sl[t] = l;
    }
    __syncthreads();

    if (t == 0) {
        float m = sl[0];
        for (int c = 1; c < NCLS_SZ; ++c) m = fmaxf(m, sl[c]);
        float e[NCLS_SZ];
        float s = 0.f;
        for (int c = 0; c < NCLS_SZ; ++c) { e[c] = expf(sl[c] - m); s += e[c]; }
        const float inv = 1.f / s;
        for (int c = 0; c < NCLS_SZ; ++c) out[b * NCLS_SZ + c] = e[c] * inv;
    }
}

extern "C" void kernel_launch(void* const* d_in, const int* in_sizes, int n_in,
                              void* d_out, int out_size, void* d_ws, size_t ws_size,
                              hipStream_t stream)
{
    const float* x     = (const float*)d_in[0];   // [B,N,F]
    const float* Lre   = (const float*)d_in[1];   // [B,N,N]
    const float* Lim   = (const float*)d_in[2];   // [B,N,N]
    const float* Wr    = (const float*)d_in[3];   // [NLAYER,F,AGG]
    const float* Wi    = (const float*)d_in[4];
    const float* fc1_w = (const float*)d_in[5];   // [FCH, 2*AGG]
    const float* fc1_b = (const float*)d_in[6];
    const float* fc2_w = (const float*)d_in[7];   // [NCLS, FCH]
    const float* fc2_b = (const float*)d_in[8];
    float* out = (float*)d_out;

    const long BNF = (long)B_SZ * N_SZ * F_SZ;    // 2,097,152 floats
    float* Tre  = (float*)d_ws;
    float* Tim  = Tre + BNF;
    float* Hre  = Tim + BNF;
    float* Him  = Hre + BNF;
    float* feat = Him + BNF;                      // B * 2*AGG floats

    const dim3 grid(AGG_SZ / BN, N_SZ / BM, B_SZ);  // (2, 8, 32)
    const long sL = (long)N_SZ * N_SZ;
    const long sH = (long)N_SZ * F_SZ;

    // layer 0: h starts as real x
    cgemm_kernel<0, 0><<<grid, 256, 0, stream>>>(
        Lre, Lim, sL, N_SZ,  x, nullptr, sH, F_SZ,  Tre, Tim, sH, F_SZ, N_SZ);
    cgemm_kernel<1, 1><<<grid, 256, 0, stream>>>(
        Tre, Tim, sH, F_SZ,  Wr, Wi, 0, AGG_SZ,  Hre, Him, sH, AGG_SZ, F_SZ);

    for (int i = 1; i < NLAYER; ++i) {
        cgemm_kernel<1, 0><<<grid, 256, 0, stream>>>(
            Lre, Lim, sL, N_SZ,  Hre, Him, sH, F_SZ,  Tre, Tim, sH, F_SZ, N_SZ);
        cgemm_kernel<1, 1><<<grid, 256, 0, stream>>>(
            Tre, Tim, sH, F_SZ,  Wr + (long)i * F_SZ * AGG_SZ, Wi + (long)i * F_SZ * AGG_SZ,
            0, AGG_SZ,  Hre, Him, sH, AGG_SZ, F_SZ);
    }

    readout_kernel<<<B_SZ, 256, 0, stream>>>(Hre, Him, feat);
    head_kernel<<<B_SZ, 256, 0, stream>>>(feat, fc1_w, fc1_b, fc2_w, fc2_b, out);
}

// Round 3
// 290.756 us; speedup vs baseline: 1.7451x; 1.7451x over previous
//
#include <hip/hip_runtime.h>
#include <hip/hip_bf16.h>
#include <math.h>

// MagNet: B=32, N=512, F=AGG=128, FCH=256, NCLS=10, NLAYER=3
// Round 3 (= round 2 resubmit after infra failure): bf16x3 MFMA complex GEMM.
//   cgemm_mfma: BM=64, BN=128, BK=64, 512 thr (8 waves, wave tile 32x32),
//   16x16x32 bf16 MFMA, A split in-kernel (L/T fp32), B pre-split planes
//   (global_load_lds, inverse-swizzled source), XOR chunk swizzle c^=(r&7).
#define B_SZ   32
#define N_SZ   512
#define F_SZ   128

typedef __attribute__((ext_vector_type(8))) short short8v;   // 8 bf16 = 4 VGPR
typedef __attribute__((ext_vector_type(4))) short short4v;
typedef __attribute__((ext_vector_type(4))) float f32x4;

typedef const __attribute__((address_space(1))) unsigned int* gas1_t;
typedef __attribute__((address_space(3))) unsigned int* las3_t;
#define GLD16(gsrc, ldst) __builtin_amdgcn_global_load_lds( \
    (gas1_t)(const void*)(gsrc), (las3_t)(unsigned int)(size_t)(void*)(ldst), 16, 0, 0)

__device__ __forceinline__ short bfh(float v) {
    __hip_bfloat16 h = __float2bfloat16(v);   // RN
    return __builtin_bit_cast(short, h);
}
__device__ __forceinline__ float bf2f(short s) {
    unsigned u = ((unsigned)(unsigned short)s) << 16;
    return __builtin_bit_cast(float, u);
}
__device__ __forceinline__ void split1(float v, short& h, short& l) {
    short hs = bfh(v);
    h = hs;
    l = bfh(v - bf2f(hs));
}

__device__ __forceinline__ void splitpack(const float4& a, const float4& b,
                                          short8v& h, short8v& l) {
    const float va[8] = {a.x, a.y, a.z, a.w, b.x, b.y, b.z, b.w};
    #pragma unroll
    for (int j = 0; j < 8; ++j) {
        short hs, ls;
        split1(va[j], hs, ls);
        h[j] = hs; l[j] = ls;
    }
}

// ---------------------------------------------------------------------------
// Complex GEMM (bf16x3):  C[b] = A[b] * B[b]
// A: fp32 re/im [M x K] row-major (lda), split in-kernel.
// B: pre-split bf16 planes, TRANSPOSED layout [N=128 rows][K] (row len = ldb).
// EPI=0: write Cr/Ci fp32 [M x 128].  EPI=1: complex-ReLU, split, write
//        4 transposed bf16 planes O* [128 rows][512] (for next layer's B).
// HAS_BIM=0: B purely real (layer-0 h = x).
// ---------------------------------------------------------------------------
template<int HAS_BIM, int EPI>
__global__ __launch_bounds__(512, 2)
void cgemm_mfma(const float* __restrict__ Ar, const float* __restrict__ Ai,
                long sA, int lda,
                const short* __restrict__ Brh, const short* __restrict__ Brl,
                const short* __restrict__ Bih, const short* __restrict__ Bil,
                long sB, int ldb, int K,
                float* __restrict__ Cr, float* __restrict__ Ci, long sC,
                short* __restrict__ Orh, short* __restrict__ Orl,
                short* __restrict__ Oih, short* __restrict__ Oil)
{
    __shared__ short As[4][64 * 64];    // planes: rh, rl, ih, il   (32 KB)
    __shared__ short Bs[4][128 * 64];   // planes: rh, rl, ih, il   (64 KB)

    const int t = threadIdx.x;
    const int b = blockIdx.y;
    const int rowBase = blockIdx.x * 64;

    const float* ArB = Ar + (long)b * sA;
    const float* AiB = Ai + (long)b * sA;
    const short* BrhB = Brh + (long)b * sB;
    const short* BrlB = Brl + (long)b * sB;
    const short* BihB = HAS_BIM ? (Bih + (long)b * sB) : nullptr;
    const short* BilB = HAS_BIM ? (Bil + (long)b * sB) : nullptr;

    // A staging: thread -> (row ra, 8-elem chunk ca)
    const int ra = t >> 3;          // 0..63
    const int ca = t & 7;           // 0..7
    const int aslot = ca ^ (ra & 7);

    // wave / lane
    const int w = t >> 6, l = t & 63;
    const int wm = w >> 2, wn = w & 3;       // wave grid 2 x 4
    const int r16 = l & 15, g = l >> 4;      // lane row / k-group

    const f32x4 z4 = {0.f, 0.f, 0.f, 0.f};
    f32x4 accR[2][2], accI[2][2];
    #pragma unroll
    for (int i = 0; i < 2; ++i)
        #pragma unroll
        for (int j = 0; j < 2; ++j) { accR[i][j] = z4; accI[i][j] = z4; }

    short8v SGN;
    #pragma unroll
    for (int j = 0; j < 8; ++j) SGN[j] = (short)0x8000;

    for (int kb = 0; kb < K; kb += 64) {
        // --- B: async global->LDS (linear dest, inverse-swizzled source) ---
        #pragma unroll
        for (int rep = 0; rep < 2; ++rep) {
            const int i = t + rep * 512;
            const int n = i >> 3, cb = i & 7;
            const long srcoff = (long)n * ldb + kb + 8 * (cb ^ (n & 7));
            GLD16(BrhB + srcoff, &Bs[0][i * 8]);
            GLD16(BrlB + srcoff, &Bs[1][i * 8]);
            if (HAS_BIM) {
                GLD16(BihB + srcoff, &Bs[2][i * 8]);
                GLD16(BilB + srcoff, &Bs[3][i * 8]);
            }
        }
        // --- A: load fp32, split, swizzled ds_write_b128 ---
        {
            const float* ar_ = ArB + (long)(rowBase + ra) * lda + kb + ca * 8;
            const float* ai_ = AiB + (long)(rowBase + ra) * lda + kb + ca * 8;
            float4 x0 = *(const float4*)ar_;
            float4 x1 = *(const float4*)(ar_ + 4);
            float4 y0 = *(const float4*)ai_;
            float4 y1 = *(const float4*)(ai_ + 4);
            short8v h8, l8;
            splitpack(x0, x1, h8, l8);
            *(short8v*)&As[0][ra * 64 + 8 * aslot] = h8;
            *(short8v*)&As[1][ra * 64 + 8 * aslot] = l8;
            splitpack(y0, y1, h8, l8);
            *(short8v*)&As[2][ra * 64 + 8 * aslot] = h8;
            *(short8v*)&As[3][ra * 64 + 8 * aslot] = l8;
        }
        __syncthreads();

        #pragma unroll
        for (int w4 = 0; w4 < 2; ++w4) {   // two K=32 windows per K-step
            short8v fArh[2], fArl[2], fAih[2], fAil[2];
            short8v fBrh[2], fBrl[2], fBih[2], fBil[2];
            #pragma unroll
            for (int tm = 0; tm < 2; ++tm) {
                const int r = wm * 32 + tm * 16 + r16;
                const int off = r * 64 + 8 * ((w4 * 4 + g) ^ (r & 7));
                fArh[tm] = *(const short8v*)&As[0][off];
                fArl[tm] = *(const short8v*)&As[1][off];
                fAih[tm] = *(const short8v*)&As[2][off];
                fAil[tm] = *(const short8v*)&As[3][off];
            }
            #pragma unroll
            for (int tn = 0; tn < 2; ++tn) {
                const int n = wn * 32 + tn * 16 + r16;
                const int off = n * 64 + 8 * ((w4 * 4 + g) ^ (n & 7));
                fBrh[tn] = *(const short8v*)&Bs[0][off];
                fBrl[tn] = *(const short8v*)&Bs[1][off];
                if (HAS_BIM) {
                    fBih[tn] = *(const short8v*)&Bs[2][off];
                    fBil[tn] = *(const short8v*)&Bs[3][off];
                }
            }
            #pragma unroll
            for (int tm = 0; tm < 2; ++tm) {
                const short8v nIh = fAih[tm] ^ SGN;   // -Ai_hi
                const short8v nIl = fAil[tm] ^ SGN;   // -Ai_lo
                #pragma unroll
                for (int tn = 0; tn < 2; ++tn) {
                    // Cr chain: Ar*Br (x3)  [- Ai*Bi (x3)]
                    accR[tm][tn] = __builtin_amdgcn_mfma_f32_16x16x32_bf16(fArh[tm], fBrh[tn], accR[tm][tn], 0, 0, 0);
                    accR[tm][tn] = __builtin_amdgcn_mfma_f32_16x16x32_bf16(fArl[tm], fBrh[tn], accR[tm][tn], 0, 0, 0);
                    accR[tm][tn] = __builtin_amdgcn_mfma_f32_16x16x32_bf16(fArh[tm], fBrl[tn], accR[tm][tn], 0, 0, 0);
                    if (HAS_BIM) {
                        accR[tm][tn] = __builtin_amdgcn_mfma_f32_16x16x32_bf16(nIh, fBih[tn], accR[tm][tn], 0, 0, 0);
                        accR[tm][tn] = __builtin_amdgcn_mfma_f32_16x16x32_bf16(nIl, fBih[tn], accR[tm][tn], 0, 0, 0);
                        accR[tm][tn] = __builtin_amdgcn_mfma_f32_16x16x32_bf16(nIh, fBil[tn], accR[tm][tn], 0, 0, 0);
                    }
                    // Ci chain: Ai*Br (x3)  [+ Ar*Bi (x3)]
                    accI[tm][tn] = __builtin_amdgcn_mfma_f32_16x16x32_bf16(fAih[tm], fBrh[tn], accI[tm][tn], 0, 0, 0);
                    accI[tm][tn] = __builtin_amdgcn_mfma_f32_16x16x32_bf16(fAil[tm], fBrh[tn], accI[tm][tn], 0, 0, 0);
                    accI[tm][tn] = __builtin_amdgcn_mfma_f32_16x16x32_bf16(fAih[tm], fBrl[tn], accI[tm][tn], 0, 0, 0);
                    if (HAS_BIM) {
                        accI[tm][tn] = __builtin_amdgcn_mfma_f32_16x16x32_bf16(fArh[tm], fBih[tn], accI[tm][tn], 0, 0, 0);
                        accI[tm][tn] = __builtin_amdgcn_mfma_f32_16x16x32_bf16(fArl[tm], fBih[tn], accI[tm][tn], 0, 0, 0);
                        accI[tm][tn] = __builtin_amdgcn_mfma_f32_16x16x32_bf16(fArh[tm], fBil[tn], accI[tm][tn], 0, 0, 0);
                    }
                }
            }
        }
        __syncthreads();
    }

    // --- epilogue ---  D layout: row = 4*g + reg, col = l&15
    #pragma unroll
    for (int tm = 0; tm < 2; ++tm) {
        #pragma unroll
        for (int tn = 0; tn < 2; ++tn) {
            f32x4 vr = accR[tm][tn], vi = accI[tm][tn];
            const int m0 = rowBase + wm * 32 + tm * 16 + 4 * g;
            const int n0 = wn * 32 + tn * 16 + r16;
            if (EPI == 0) {
                #pragma unroll
                for (int rr = 0; rr < 4; ++rr) {
                    Cr[(long)b * sC + (long)(m0 + rr) * 128 + n0] = vr[rr];
                    Ci[(long)b * sC + (long)(m0 + rr) * 128 + n0] = vi[rr];
                }
            } else {
                short4v rh, rl, ih, il;
                #pragma unroll
                for (int rr = 0; rr < 4; ++rr) {
                    float cr = vr[rr], cim = vi[rr];
                    if (cr < 0.f) { cr = 0.f; cim = 0.f; }   // complex ReLU
                    short hs, ls;
                    split1(cr, hs, ls);  rh[rr] = hs; rl[rr] = ls;
                    split1(cim, hs, ls); ih[rr] = hs; il[rr] = ls;
                }
                const long base = ((long)b * 128 + n0) * 512 + m0;  // transposed
                *(short4v*)(Orh + base) = rh;
                *(short4v*)(Orl + base) = rl;
                *(short4v*)(Oih + base) = ih;
                *(short4v*)(Oil + base) = il;
            }
        }
    }
}

// x [B,512,128] fp32 -> transposed bf16 planes x^T [B,128,512] hi/lo
__global__ __launch_bounds__(256)
void split_x_kernel(const float* __restrict__ x, short* __restrict__ Xh,
                    short* __restrict__ Xl)
{
    __shared__ float XT[128][65];
    const int b = blockIdx.x >> 3, nc = blockIdx.x & 7;
    const int t = threadIdx.x;
    {
        const int nl = t & 63, fc = t >> 6;   // fc 0..3 (32-feature strip)
        const float* src = x + ((long)b * 512 + nc * 64 + nl) * 128 + fc * 32;
        #pragma unroll
        for (int q = 0; q < 8; ++q) {
            float4 v = *(const float4*)(src + q * 4);
            XT[fc * 32 + q * 4 + 0][nl] = v.x;
            XT[fc * 32 + q * 4 + 1][nl] = v.y;
            XT[fc * 32 + q * 4 + 2][nl] = v.z;
            XT[fc * 32 + q * 4 + 3][nl] = v.w;
        }
    }
    __syncthreads();
    const int f = t >> 1, half = t & 1;
    short8v H[4], L[4];
    #pragma unroll
    for (int i = 0; i < 32; ++i) {
        short hs, ls;
        split1(XT[f][half * 32 + i], hs, ls);
        H[i >> 3][i & 7] = hs;
        L[i >> 3][i & 7] = ls;
    }
    const long base = ((long)b * 128 + f) * 512 + nc * 64 + half * 32;
    #pragma unroll
    for (int q = 0; q < 4; ++q) {
        *(short8v*)(Xh + base + q * 8) = H[q];
        *(short8v*)(Xl + base + q * 8) = L[q];
    }
}

// W [3,128,128] fp32 re/im -> transposed planes W^T [3,128 n,128 k] x4
__global__ __launch_bounds__(128)
void split_w_kernel(const float* __restrict__ Wr, const float* __restrict__ Wi,
                    short* __restrict__ Wrh, short* __restrict__ Wrl,
                    short* __restrict__ Wih, short* __restrict__ Wil)
{
    const int layer = blockIdx.x >> 7, n = blockIdx.x & 127;
    const int k = threadIdx.x;
    const long src = ((long)layer * 128 + k) * 128 + n;
    const long dst = ((long)layer * 128 + n) * 128 + k;
    short hs, ls;
    split1(Wr[src], hs, ls); Wrh[dst] = hs; Wrl[dst] = ls;
    split1(Wi[src], hs, ls); Wih[dst] = hs; Wil[dst] = ls;
}

// partial mean over 64 nodes: part[b*8+nc][256]
__global__ __launch_bounds__(256)
void readout_kernel(const short* __restrict__ Hrh, const short* __restrict__ Hrl,
                    const short* __restrict__ Hih, const short* __restrict__ Hil,
                    float* __restrict__ part)
{
    const int b = blockIdx.x >> 3, nc = blockIdx.x & 7;
    const int t = threadIdx.x;
    const int f = t & 127;
    const short* Ph = (t < 128) ? Hrh : Hih;
    const short* Pl = (t < 128) ? Hrl : Hil;
    const long base = ((long)b * 128 + f) * 512 + nc * 64;
    float s = 0.f;
    #pragma unroll
    for (int q = 0; q < 8; ++q) {
        short8v vh = *(const short8v*)(Ph + base + q * 8);
        short8v vl = *(const short8v*)(Pl + base + q * 8);
        #pragma unroll
        for (int j = 0; j < 8; ++j) s += bf2f(vh[j]) + bf2f(vl[j]);
    }
    part[((long)b * 8 + nc) * 256 + t] = s;
}

// fc1+relu -> fc2 -> softmax (one block per batch row)
__global__ __launch_bounds__(256)
void head_kernel(const float* __restrict__ part,
                 const float* __restrict__ w1, const float* __restrict__ b1,
                 const float* __restrict__ w2, const float* __restrict__ b2,
                 float* __restrict__ out)
{
    __shared__ float sf[256];
    __shared__ float sz[256];
    __shared__ float sl[16];
    const int b = blockIdx.x;
    const int t = threadIdx.x;

    float s = 0.f;
    #pragma unroll
    for (int nc = 0; nc < 8; ++nc) s += part[((long)b * 8 + nc) * 256 + t];
    sf[t] = s * (1.0f / 512.0f);
    __syncthreads();

    float acc = b1[t];
    const float* wrow = w1 + (long)t * 256;
    #pragma unroll 8
    for (int j = 0; j < 256; ++j) acc = fmaf(sf[j], wrow[j], acc);
    sz[t] = fmaxf(acc, 0.f);
    __syncthreads();

    if (t < 10) {
        float lg = b2[t];
        const float* w2r = w2 + (long)t * 256;
        #pragma unroll 8
        for (int j = 0; j < 256; ++j) lg = fmaf(sz[j], w2r[j], lg);
        sl[t] = lg;
    }
    __syncthreads();
    if (t == 0) {
        float m = sl[0];
        for (int c = 1; c < 10; ++c) m = fmaxf(m, sl[c]);
        float e[10]; float ss = 0.f;
        for (int c = 0; c < 10; ++c) { e[c] = expf(sl[c] - m); ss += e[c]; }
        const float inv = 1.f / ss;
        for (int c = 0; c < 10; ++c) out[b * 10 + c] = e[c] * inv;
    }
}

extern "C" void kernel_launch(void* const* d_in, const int* in_sizes, int n_in,
                              void* d_out, int out_size, void* d_ws, size_t ws_size,
                              hipStream_t stream)
{
    const float* x     = (const float*)d_in[0];   // [32,512,128]
    const float* Lre   = (const float*)d_in[1];   // [32,512,512]
    const float* Lim   = (const float*)d_in[2];
    const float* Wr    = (const float*)d_in[3];   // [3,128,128]
    const float* Wi    = (const float*)d_in[4];
    const float* fc1_w = (const float*)d_in[5];
    const float* fc1_b = (const float*)d_in[6];
    const float* fc2_w = (const float*)d_in[7];
    const float* fc2_b = (const float*)d_in[8];
    float* out = (float*)d_out;

    const long BNF = (long)B_SZ * N_SZ * F_SZ;    // 2,097,152
    float* Tre = (float*)d_ws;
    float* Tim = Tre + BNF;
    short* Hrh = (short*)(Tim + BNF);   // also aliases x^T hi before layer 0
    short* Hrl = Hrh + BNF;             // also aliases x^T lo
    short* Hih = Hrl + BNF;
    short* Hil = Hih + BNF;
    short* Wrh = Hil + BNF;             // [3,128,128]
    short* Wrl = Wrh + 3 * 128 * 128;
    short* Wih = Wrl + 3 * 128 * 128;
    short* Wil = Wih + 3 * 128 * 128;
    float* part = (float*)(Wil + 3 * 128 * 128);  // [32*8, 256]

    const long sL = (long)N_SZ * N_SZ;        // 262144
    const long sH = (long)F_SZ * N_SZ;        // 65536 (transposed planes / T)
    const dim3 ggrid(8, 32);

    split_w_kernel<<<384, 128, 0, stream>>>(Wr, Wi, Wrh, Wrl, Wih, Wil);
    split_x_kernel<<<256, 256, 0, stream>>>(x, Hrh, Hrl);

    for (int layer = 0; layer < 3; ++layer) {
        if (layer == 0) {
            // agg: T = L * x   (B real)
            cgemm_mfma<0, 0><<<ggrid, 512, 0, stream>>>(
                Lre, Lim, sL, 512, Hrh, Hrl, nullptr, nullptr, sH, 512, 512,
                Tre, Tim, sH, nullptr, nullptr, nullptr, nullptr);
        } else {
            // agg: T = L * h
            cgemm_mfma<1, 0><<<ggrid, 512, 0, stream>>>(
                Lre, Lim, sL, 512, Hrh, Hrl, Hih, Hil, sH, 512, 512,
                Tre, Tim, sH, nullptr, nullptr, nullptr, nullptr);
        }
        // transform: h = crelu(T * W[layer]) -> transposed planes
        const long wo = (long)layer * 128 * 128;
        cgemm_mfma<1, 1><<<ggrid, 512, 0, stream>>>(
            Tre, Tim, sH, 128, Wrh + wo, Wrl + wo, Wih + wo, Wil + wo, 0, 128, 128,
            nullptr, nullptr, 0, Hrh, Hrl, Hih, Hil);
    }

    readout_kernel<<<256, 256, 0, stream>>>(Hrh, Hrl, Hih, Hil, part);
    head_kernel<<<32, 256, 0, stream>>>(part, fc1_w, fc1_b, fc2_w, fc2_b, out);
}